// Round 2
// baseline (2437.775 us; speedup 1.0000x reference)
//
#include <hip/hip_runtime.h>
#include <hip/hip_bf16.h>

// FocalNet block, MI355X gfx950. bf16 MFMA for all GEMMs.
// Dims fixed by setup_inputs: B=64, H=W=56, C=128, hidden=512.
// Workspace budget kept ~107 MB: d_out doubles as conv ping-pong scratch
// (2 bf16 NT*128 planes fit exactly in NT*128 fp32), MLP runs in 4 hidden
// chunks through one reusable plane, ctx_all accumulated progressively.

#define NT    200704   // B*H*W tokens
#define CC    128
#define HH    56
#define WW    56
#define BB    64

typedef short short8 __attribute__((ext_vector_type(8)));
typedef float f32x4  __attribute__((ext_vector_type(4)));
typedef unsigned short ushort_t;

__device__ __forceinline__ float b2f(unsigned short u) {
    union { float f; unsigned int i; } v; v.i = ((unsigned int)u) << 16; return v.f;
}
__device__ __forceinline__ unsigned short f2b(float f) {
    __hip_bfloat16 h = __float2bfloat16(f);
    union { __hip_bfloat16 h; unsigned short u; } v; v.h = h; return v.u;
}
__device__ __forceinline__ float gelu(float x) {
    return 0.5f * x * (1.0f + erff(x * 0.70710678118654752f));
}

// ---------------- weight prep: fp32 (K,M) row-major -> bf16 (M,K) ----------------
__global__ void transpose_bf16_k(const float* __restrict__ src, unsigned short* __restrict__ dst,
                                 int K, int M, int src_ld) {
    int idx = blockIdx.x * 256 + threadIdx.x;
    if (idx >= K * M) return;
    int k = idx / M, m = idx - k * M;
    dst[m * K + k] = f2b(src[k * src_ld + m]);
}

// fc2_w (512,128) -> chunk-major (4, 128, 128): dst[hc][m][kl] = src[hc*128+kl][m]
__global__ void transpose_fc2c_k(const float* __restrict__ src, unsigned short* __restrict__ dst) {
    int idx = blockIdx.x * 256 + threadIdx.x;
    if (idx >= 512 * 128) return;
    int k = idx >> 7, m = idx & 127;
    int hc = k >> 7, kl = k & 127;
    dst[hc * 16384 + m * 128 + kl] = f2b(src[k * 128 + m]);
}

__global__ void zero_k(float* p, int n) {
    int i = blockIdx.x * 256 + threadIdx.x;
    if (i < n) p[i] = 0.0f;
}

// ---------------- LN1 + gate dots (wave per token) ----------------
__global__ __launch_bounds__(256) void ln1_gates_k(
    const float* __restrict__ x, const float* __restrict__ g, const float* __restrict__ bta,
    const float* __restrict__ fw, const float* __restrict__ fb,
    unsigned short* __restrict__ ybf, float* __restrict__ gates)
{
    int lane = threadIdx.x & 63, wv = threadIdx.x >> 6;
    int token = blockIdx.x * 4 + wv;
    float2 xv = *(const float2*)&x[(size_t)token * CC + lane * 2];
    float s = xv.x + xv.y;
    for (int o = 32; o; o >>= 1) s += __shfl_xor(s, o);
    float mu = s * (1.0f / 128.0f);
    float d0 = xv.x - mu, d1 = xv.y - mu;
    float q2 = d0 * d0 + d1 * d1;
    for (int o = 32; o; o >>= 1) q2 += __shfl_xor(q2, o);
    float rs = rsqrtf(q2 * (1.0f / 128.0f) + 1e-5f);
    float y0 = d0 * rs * g[2 * lane] + bta[2 * lane];
    float y1 = d1 * rs * g[2 * lane + 1] + bta[2 * lane + 1];
    unsigned int pk = (unsigned int)f2b(y0) | ((unsigned int)f2b(y1) << 16);
    ((unsigned int*)ybf)[(size_t)token * 64 + lane] = pk;
    // gates = y @ f_w[:, 256:260] + f_b[256:260]
    float ga[4];
    #pragma unroll
    for (int gg = 0; gg < 4; gg++)
        ga[gg] = y0 * fw[(2 * lane) * 260 + 256 + gg] + y1 * fw[(2 * lane + 1) * 260 + 256 + gg];
    for (int o = 32; o; o >>= 1) {
        #pragma unroll
        for (int gg = 0; gg < 4; gg++) ga[gg] += __shfl_xor(ga[gg], o);
    }
    if (lane == 0) {
        float4 gv = make_float4(ga[0] + fb[256], ga[1] + fb[257], ga[2] + fb[258], ga[3] + fb[259]);
        *(float4*)&gates[(size_t)token * 4] = gv;
    }
}

// ---------------- LN2 (wave per token) ----------------
__global__ __launch_bounds__(256) void ln2_k(
    const float* __restrict__ x, const float* __restrict__ g, const float* __restrict__ bta,
    unsigned short* __restrict__ ybf)
{
    int lane = threadIdx.x & 63, wv = threadIdx.x >> 6;
    int token = blockIdx.x * 4 + wv;
    float2 xv = *(const float2*)&x[(size_t)token * CC + lane * 2];
    float s = xv.x + xv.y;
    for (int o = 32; o; o >>= 1) s += __shfl_xor(s, o);
    float mu = s * (1.0f / 128.0f);
    float d0 = xv.x - mu, d1 = xv.y - mu;
    float q2 = d0 * d0 + d1 * d1;
    for (int o = 32; o; o >>= 1) q2 += __shfl_xor(q2, o);
    float rs = rsqrtf(q2 * (1.0f / 128.0f) + 1e-5f);
    float y0 = d0 * rs * g[2 * lane] + bta[2 * lane];
    float y1 = d1 * rs * g[2 * lane + 1] + bta[2 * lane + 1];
    unsigned int pk = (unsigned int)f2b(y0) | ((unsigned int)f2b(y1) << 16);
    ((unsigned int*)ybf)[(size_t)token * 64 + lane] = pk;
}

// ---------------- GEMM: A (NT,K) bf16 row-major, Wt (M,K) bf16 row-major ----------------
// 128x128 block tile, BK=64 chunks, 4 waves 2x2, each wave 64x64 via 4x4 mfma_16x16x32.
// MODE 0: out bf16 = v + bias
// MODE 1: out bf16 = (v + bias) * q    (outp may alias qbf; per-thread 1:1 RMW)
// MODE 2: out f32  = v + bias + xres   (outp may alias xres; per-thread 1:1 RMW)
// MODE 3: out bf16 = gelu(v + bias)
template<int MODE>
__global__ __launch_bounds__(256) void gemm_k(
    const unsigned short* __restrict__ A, const unsigned short* __restrict__ Wt,
    const float* __restrict__ bias, int K, int out_ld,
    void* outp, const unsigned short* qbf, const float* xres)
{
    __shared__ unsigned short As[128 * 72];
    __shared__ unsigned short Bs[128 * 72];
    const int tid = threadIdx.x;
    const int row0 = blockIdx.x * 128;
    const int colt = blockIdx.y;
    const unsigned short* Wtt = Wt + (size_t)colt * 128 * K;
    const int lane = tid & 63, wv = tid >> 6;
    const int wy = wv >> 1, wx = wv & 1;
    const int q4 = lane >> 4, l16 = lane & 15;

    f32x4 acc[4][4];
    #pragma unroll
    for (int i = 0; i < 4; i++)
        #pragma unroll
        for (int j = 0; j < 4; j++) acc[i][j] = (f32x4)0.0f;

    for (int k0 = 0; k0 < K; k0 += 64) {
        __syncthreads();
        #pragma unroll
        for (int i = 0; i < 4; i++) {
            int li = tid + i * 256;
            int r = li >> 3, c8 = (li & 7) * 8;
            *(uint4*)&As[r * 72 + c8] = *(const uint4*)&A[(size_t)(row0 + r) * K + k0 + c8];
            *(uint4*)&Bs[r * 72 + c8] = *(const uint4*)&Wtt[(size_t)r * K + k0 + c8];
        }
        __syncthreads();
        #pragma unroll
        for (int kk = 0; kk < 64; kk += 32) {
            short8 af[4], bf[4];
            #pragma unroll
            for (int i = 0; i < 4; i++)
                af[i] = *(const short8*)&As[(wy * 64 + i * 16 + l16) * 72 + kk + q4 * 8];
            #pragma unroll
            for (int j = 0; j < 4; j++)
                bf[j] = *(const short8*)&Bs[(wx * 64 + j * 16 + l16) * 72 + kk + q4 * 8];
            #pragma unroll
            for (int i = 0; i < 4; i++)
                #pragma unroll
                for (int j = 0; j < 4; j++)
                    acc[i][j] = __builtin_amdgcn_mfma_f32_16x16x32_bf16(af[i], bf[j], acc[i][j], 0, 0, 0);
        }
    }

    // epilogue: C/D layout col=lane&15, row=(lane>>4)*4+r  [m89-verified]
    #pragma unroll
    for (int i = 0; i < 4; i++) {
        #pragma unroll
        for (int j = 0; j < 4; j++) {
            #pragma unroll
            for (int r = 0; r < 4; r++) {
                int row = row0 + wy * 64 + i * 16 + q4 * 4 + r;
                int gcol = colt * 128 + wx * 64 + j * 16 + l16;
                float v = acc[i][j][r] + bias[gcol];
                size_t oi = (size_t)row * out_ld + gcol;
                if (MODE == 0) {
                    ((unsigned short*)outp)[oi] = f2b(v);
                } else if (MODE == 1) {
                    float qv = b2f(qbf[(size_t)row * CC + gcol]);
                    ((unsigned short*)outp)[oi] = f2b(v * qv);
                } else if (MODE == 2) {
                    ((float*)outp)[oi] = v + xres[(size_t)row * CC + gcol];
                } else { // MODE 3
                    ((unsigned short*)outp)[oi] = f2b(gelu(v));
                }
            }
        }
    }
}

// ---------------- depthwise conv (SAME, zero pad) + GELU + gated accumulate ----------------
// out = gelu(conv(in));  acc = (L==0 ? 0 : acc) + gate[L] * out
template<int R, int L>
__global__ __launch_bounds__(256) void dwconv_k(
    const unsigned short* __restrict__ in, const float* __restrict__ w,
    unsigned short* __restrict__ out, const float* __restrict__ gates,
    unsigned short* acc)
{
    constexpr int KS = 2 * R + 1;
    int t = threadIdx.x;
    int c = t & 127, pix = t >> 7;
    int token = blockIdx.x * 2 + pix;
    int b = token / (HH * WW);
    int rem = token - b * (HH * WW);
    int h = rem / WW;
    int w0 = rem - h * WW;
    float s = 0.0f;
    #pragma unroll
    for (int dh = -R; dh <= R; dh++) {
        int hh = h + dh;
        if ((unsigned)hh < (unsigned)HH) {
            #pragma unroll
            for (int dw = -R; dw <= R; dw++) {
                int wc = w0 + dw;
                if ((unsigned)wc < (unsigned)WW) {
                    s += b2f(in[((size_t)(b * HH * WW) + hh * WW + wc) * CC + c]) *
                         w[((dh + R) * KS + (dw + R)) * CC + c];
                }
            }
        }
    }
    float go = gelu(s);
    size_t idx = (size_t)token * CC + c;
    out[idx] = f2b(go);
    float gval = gates[(size_t)token * 4 + L];
    float prev = (L == 0) ? 0.0f : b2f(acc[idx]);
    acc[idx] = f2b(prev + go * gval);
}

// ---------------- global mean over H*W, two-stage ----------------
__global__ void mean_part_k(const unsigned short* __restrict__ ctx2, float* __restrict__ part) {
    int b = blockIdx.x >> 4, ch = blockIdx.x & 15;
    int c = threadIdx.x; // 128 threads
    float s = 0.0f;
    size_t base = ((size_t)b * (HH * WW) + ch * 196) * CC + c;
    for (int p = 0; p < 196; p++) s += b2f(ctx2[base + (size_t)p * CC]);
    part[blockIdx.x * CC + c] = s;
}
__global__ void mean_fin_k(const float* __restrict__ part, float* __restrict__ cg) {
    int b = blockIdx.x, c = threadIdx.x;
    float s = 0.0f;
    for (int i = 0; i < 16; i++) s += part[(b * 16 + i) * CC + c];
    cg[b * CC + c] = gelu(s * (1.0f / 3136.0f));
}

// ---------------- acc += cg[b] * gate3 ----------------
__global__ __launch_bounds__(256) void addg3_k(
    unsigned short* acc, const float* __restrict__ gates, const float* __restrict__ cg)
{
    size_t idx = (size_t)blockIdx.x * 256 + threadIdx.x;
    int token = (int)(idx >> 7);
    int c = (int)(idx & 127);
    int b = token / (HH * WW);
    acc[idx] = f2b(b2f(acc[idx]) + cg[b * CC + c] * gates[(size_t)token * 4 + 3]);
}

extern "C" void kernel_launch(void* const* d_in, const int* in_sizes, int n_in,
                              void* d_out, int out_size, void* d_ws, size_t ws_size,
                              hipStream_t stream) {
    (void)in_sizes; (void)n_in; (void)out_size; (void)ws_size;
    const float* x      = (const float*)d_in[0];
    const float* f_w    = (const float*)d_in[1];
    const float* f_b    = (const float*)d_in[2];
    const float* k0     = (const float*)d_in[3];
    const float* k1     = (const float*)d_in[4];
    const float* k2     = (const float*)d_in[5];
    const float* h_w    = (const float*)d_in[6];
    const float* h_b    = (const float*)d_in[7];
    const float* proj_w = (const float*)d_in[8];
    const float* proj_b = (const float*)d_in[9];
    const float* ln1_g  = (const float*)d_in[10];
    const float* ln1_b  = (const float*)d_in[11];
    const float* ln2_g  = (const float*)d_in[12];
    const float* ln2_b  = (const float*)d_in[13];
    const float* fc1_w  = (const float*)d_in[14];
    const float* fc1_b  = (const float*)d_in[15];
    const float* fc2_w  = (const float*)d_in[16];
    const float* fc2_b  = (const float*)d_in[17];
    float* out = (float*)d_out;

    // ---- workspace bump allocator (256B aligned), total ~106.9 MB ----
    size_t off = 0;
    auto alloc = [&](size_t bytes) -> char* {
        char* p = (char*)d_ws + off;
        off += (bytes + 255) & ~(size_t)255;
        return p;
    };
    unsigned short* wt_f    = (unsigned short*)alloc(256 * 128 * 2);
    unsigned short* wt_h    = (unsigned short*)alloc(128 * 128 * 2);
    unsigned short* wt_proj = (unsigned short*)alloc(128 * 128 * 2);
    unsigned short* wt_fc1  = (unsigned short*)alloc(512 * 128 * 2);
    unsigned short* wt_fc2c = (unsigned short*)alloc(512 * 128 * 2);
    float*          zeros   = (float*)alloc(128 * 4);
    unsigned short* Y       = (unsigned short*)alloc((size_t)NT * CC * 2); // y -> ctx_all acc -> m
    unsigned short* Q       = (unsigned short*)alloc((size_t)NT * CC * 2); // q -> x_out -> G chunks
    float*          gates   = (float*)alloc((size_t)NT * 4 * 4);
    float*          part    = (float*)alloc(BB * 16 * CC * 4);
    float*          cg      = (float*)alloc(BB * CC * 4);

    // d_out (NT*128 fp32) doubles as two bf16 NT*128 planes for conv ping-pong
    unsigned short* p0 = (unsigned short*)d_out;
    unsigned short* p1 = p0 + (size_t)NT * CC;

    // ---- 0. weight prep ----
    transpose_bf16_k<<<(128 * 256 + 255) / 256, 256, 0, stream>>>(f_w, wt_f, 128, 256, 260);
    transpose_bf16_k<<<(128 * 128 + 255) / 256, 256, 0, stream>>>(h_w, wt_h, 128, 128, 128);
    transpose_bf16_k<<<(128 * 128 + 255) / 256, 256, 0, stream>>>(proj_w, wt_proj, 128, 128, 128);
    transpose_bf16_k<<<(128 * 512 + 255) / 256, 256, 0, stream>>>(fc1_w, wt_fc1, 128, 512, 512);
    transpose_fc2c_k<<<(512 * 128 + 255) / 256, 256, 0, stream>>>(fc2_w, wt_fc2c);
    zero_k<<<1, 256, 0, stream>>>(zeros, 128);

    // ---- 1. LN1 + gates -> Y, gates ----
    ln1_gates_k<<<NT / 4, 256, 0, stream>>>(x, ln1_g, ln1_b, f_w, f_b, Y, gates);

    // ---- 2. t = y @ f_w : q (cols 0..127) -> Q, ctx (cols 128..255) -> p1 ----
    gemm_k<0><<<dim3(NT / 128, 1), 256, 0, stream>>>(Y, wt_f, f_b, 128, 128, Q, nullptr, nullptr);
    gemm_k<0><<<dim3(NT / 128, 1), 256, 0, stream>>>(Y, wt_f + 128 * 128, f_b + 128, 128, 128, p1, nullptr, nullptr);

    // ---- 3-5. focal conv chain, ping-pong in d_out planes, acc in Y ----
    dwconv_k<1, 0><<<NT / 2, 256, 0, stream>>>(p1, k0, p0, gates, Y);
    dwconv_k<2, 1><<<NT / 2, 256, 0, stream>>>(p0, k1, p1, gates, Y);
    dwconv_k<3, 2><<<NT / 2, 256, 0, stream>>>(p1, k2, p0, gates, Y);

    // ---- 6-7. global context from ctx2 (p0) ----
    mean_part_k<<<BB * 16, 128, 0, stream>>>(p0, part);
    mean_fin_k<<<BB, 128, 0, stream>>>(part, cg);

    // ---- 8. ctx_all += cg * gate3 (in Y) ----
    addg3_k<<<NT * CC / 256, 256, 0, stream>>>(Y, gates, cg);

    // ---- 9. modulator GEMM, epilogue * q -> x_out (in place over Q) ----
    gemm_k<1><<<dim3(NT / 128, 1), 256, 0, stream>>>(Y, wt_h, h_b, 128, 128, Q, Q, nullptr);

    // ---- 10. proj GEMM, epilogue + x -> x1 (d_out, conv planes dead) ----
    gemm_k<2><<<dim3(NT / 128, 1), 256, 0, stream>>>(Q, wt_proj, proj_b, 128, 128, out, nullptr, x);

    // ---- 11. LN2 -> m (Y region) ----
    ln2_k<<<NT / 4, 256, 0, stream>>>(out, ln2_g, ln2_b, Y);

    // ---- 12. MLP in 4 hidden chunks: G = gelu(m@fc1_hc) -> Q; out += G@fc2_hc ----
    for (int hc = 0; hc < 4; hc++) {
        gemm_k<3><<<dim3(NT / 128, 1), 256, 0, stream>>>(Y, wt_fc1 + hc * 16384, fc1_b + hc * 128,
                                                         128, 128, Q, nullptr, nullptr);
        gemm_k<2><<<dim3(NT / 128, 1), 256, 0, stream>>>(Q, wt_fc2c + hc * 16384,
                                                         hc == 0 ? fc2_b : zeros,
                                                         128, 128, out, nullptr, out);
    }
}

// Round 3
// 1324.482 us; speedup vs baseline: 1.8406x; 1.8406x over previous
//
#include <hip/hip_runtime.h>
#include <hip/hip_bf16.h>

// FocalNet block, MI355X gfx950. bf16 MFMA for all GEMMs.
// Dims fixed by setup_inputs: B=64, H=W=56, C=128, hidden=512.
// R3: register-tiled vectorized depthwise conv (was scalar-load bound, 845us for 7x7).

#define NT    200704   // B*H*W tokens
#define CC    128
#define HH    56
#define WW    56
#define BB    64

typedef short short8 __attribute__((ext_vector_type(8)));
typedef float f32x4  __attribute__((ext_vector_type(4)));

__device__ __forceinline__ float b2f(unsigned short u) {
    union { float f; unsigned int i; } v; v.i = ((unsigned int)u) << 16; return v.f;
}
__device__ __forceinline__ unsigned short f2b(float f) {
    __hip_bfloat16 h = __float2bfloat16(f);
    union { __hip_bfloat16 h; unsigned short u; } v; v.h = h; return v.u;
}
__device__ __forceinline__ float gelu(float x) {
    return 0.5f * x * (1.0f + erff(x * 0.70710678118654752f));
}
// unpack 4 bf16 (uint2) -> 4 fp32
__device__ __forceinline__ void cvt4(uint2 p, float* o) {
    union { float f; unsigned int i; } v;
    v.i = p.x << 16;         o[0] = v.f;
    v.i = p.x & 0xffff0000u; o[1] = v.f;
    v.i = p.y << 16;         o[2] = v.f;
    v.i = p.y & 0xffff0000u; o[3] = v.f;
}
__device__ __forceinline__ uint2 pack4(const float* s) {
    uint2 r;
    r.x = (unsigned int)f2b(s[0]) | ((unsigned int)f2b(s[1]) << 16);
    r.y = (unsigned int)f2b(s[2]) | ((unsigned int)f2b(s[3]) << 16);
    return r;
}

// ---------------- weight prep: fp32 (K,M) row-major -> bf16 (M,K) ----------------
__global__ void transpose_bf16_k(const float* __restrict__ src, unsigned short* __restrict__ dst,
                                 int K, int M, int src_ld) {
    int idx = blockIdx.x * 256 + threadIdx.x;
    if (idx >= K * M) return;
    int k = idx / M, m = idx - k * M;
    dst[m * K + k] = f2b(src[k * src_ld + m]);
}

// fc2_w (512,128) -> chunk-major (4, 128, 128): dst[hc][m][kl] = src[hc*128+kl][m]
__global__ void transpose_fc2c_k(const float* __restrict__ src, unsigned short* __restrict__ dst) {
    int idx = blockIdx.x * 256 + threadIdx.x;
    if (idx >= 512 * 128) return;
    int k = idx >> 7, m = idx & 127;
    int hc = k >> 7, kl = k & 127;
    dst[hc * 16384 + m * 128 + kl] = f2b(src[k * 128 + m]);
}

__global__ void zero_k(float* p, int n) {
    int i = blockIdx.x * 256 + threadIdx.x;
    if (i < n) p[i] = 0.0f;
}

// ---------------- LN1 + gate dots (wave per token) ----------------
__global__ __launch_bounds__(256) void ln1_gates_k(
    const float* __restrict__ x, const float* __restrict__ g, const float* __restrict__ bta,
    const float* __restrict__ fw, const float* __restrict__ fb,
    unsigned short* __restrict__ ybf, float* __restrict__ gates)
{
    int lane = threadIdx.x & 63, wv = threadIdx.x >> 6;
    int token = blockIdx.x * 4 + wv;
    float2 xv = *(const float2*)&x[(size_t)token * CC + lane * 2];
    float s = xv.x + xv.y;
    for (int o = 32; o; o >>= 1) s += __shfl_xor(s, o);
    float mu = s * (1.0f / 128.0f);
    float d0 = xv.x - mu, d1 = xv.y - mu;
    float q2 = d0 * d0 + d1 * d1;
    for (int o = 32; o; o >>= 1) q2 += __shfl_xor(q2, o);
    float rs = rsqrtf(q2 * (1.0f / 128.0f) + 1e-5f);
    float y0 = d0 * rs * g[2 * lane] + bta[2 * lane];
    float y1 = d1 * rs * g[2 * lane + 1] + bta[2 * lane + 1];
    unsigned int pk = (unsigned int)f2b(y0) | ((unsigned int)f2b(y1) << 16);
    ((unsigned int*)ybf)[(size_t)token * 64 + lane] = pk;
    // gates = y @ f_w[:, 256:260] + f_b[256:260]
    float ga[4];
    #pragma unroll
    for (int gg = 0; gg < 4; gg++)
        ga[gg] = y0 * fw[(2 * lane) * 260 + 256 + gg] + y1 * fw[(2 * lane + 1) * 260 + 256 + gg];
    for (int o = 32; o; o >>= 1) {
        #pragma unroll
        for (int gg = 0; gg < 4; gg++) ga[gg] += __shfl_xor(ga[gg], o);
    }
    if (lane == 0) {
        float4 gv = make_float4(ga[0] + fb[256], ga[1] + fb[257], ga[2] + fb[258], ga[3] + fb[259]);
        *(float4*)&gates[(size_t)token * 4] = gv;
    }
}

// ---------------- LN2 (wave per token) ----------------
__global__ __launch_bounds__(256) void ln2_k(
    const float* __restrict__ x, const float* __restrict__ g, const float* __restrict__ bta,
    unsigned short* __restrict__ ybf)
{
    int lane = threadIdx.x & 63, wv = threadIdx.x >> 6;
    int token = blockIdx.x * 4 + wv;
    float2 xv = *(const float2*)&x[(size_t)token * CC + lane * 2];
    float s = xv.x + xv.y;
    for (int o = 32; o; o >>= 1) s += __shfl_xor(s, o);
    float mu = s * (1.0f / 128.0f);
    float d0 = xv.x - mu, d1 = xv.y - mu;
    float q2 = d0 * d0 + d1 * d1;
    for (int o = 32; o; o >>= 1) q2 += __shfl_xor(q2, o);
    float rs = rsqrtf(q2 * (1.0f / 128.0f) + 1e-5f);
    float y0 = d0 * rs * g[2 * lane] + bta[2 * lane];
    float y1 = d1 * rs * g[2 * lane + 1] + bta[2 * lane + 1];
    unsigned int pk = (unsigned int)f2b(y0) | ((unsigned int)f2b(y1) << 16);
    ((unsigned int*)ybf)[(size_t)token * 64 + lane] = pk;
}

// ---------------- GEMM: A (NT,K) bf16 row-major, Wt (M,K) bf16 row-major ----------------
// 128x128 block tile, BK=64 chunks, 4 waves 2x2, each wave 64x64 via 4x4 mfma_16x16x32.
// MODE 0: out bf16 = v + bias
// MODE 1: out bf16 = (v + bias) * q    (outp may alias qbf; per-thread 1:1 RMW)
// MODE 2: out f32  = v + bias + xres   (outp may alias xres; per-thread 1:1 RMW)
// MODE 3: out bf16 = gelu(v + bias)
template<int MODE>
__global__ __launch_bounds__(256) void gemm_k(
    const unsigned short* __restrict__ A, const unsigned short* __restrict__ Wt,
    const float* __restrict__ bias, int K, int out_ld,
    void* outp, const unsigned short* qbf, const float* xres)
{
    __shared__ unsigned short As[128 * 72];
    __shared__ unsigned short Bs[128 * 72];
    const int tid = threadIdx.x;
    const int row0 = blockIdx.x * 128;
    const int colt = blockIdx.y;
    const unsigned short* Wtt = Wt + (size_t)colt * 128 * K;
    const int lane = tid & 63, wv = tid >> 6;
    const int wy = wv >> 1, wx = wv & 1;
    const int q4 = lane >> 4, l16 = lane & 15;

    f32x4 acc[4][4];
    #pragma unroll
    for (int i = 0; i < 4; i++)
        #pragma unroll
        for (int j = 0; j < 4; j++) acc[i][j] = (f32x4)0.0f;

    for (int k0 = 0; k0 < K; k0 += 64) {
        __syncthreads();
        #pragma unroll
        for (int i = 0; i < 4; i++) {
            int li = tid + i * 256;
            int r = li >> 3, c8 = (li & 7) * 8;
            *(uint4*)&As[r * 72 + c8] = *(const uint4*)&A[(size_t)(row0 + r) * K + k0 + c8];
            *(uint4*)&Bs[r * 72 + c8] = *(const uint4*)&Wtt[(size_t)r * K + k0 + c8];
        }
        __syncthreads();
        #pragma unroll
        for (int kk = 0; kk < 64; kk += 32) {
            short8 af[4], bf[4];
            #pragma unroll
            for (int i = 0; i < 4; i++)
                af[i] = *(const short8*)&As[(wy * 64 + i * 16 + l16) * 72 + kk + q4 * 8];
            #pragma unroll
            for (int j = 0; j < 4; j++)
                bf[j] = *(const short8*)&Bs[(wx * 64 + j * 16 + l16) * 72 + kk + q4 * 8];
            #pragma unroll
            for (int i = 0; i < 4; i++)
                #pragma unroll
                for (int j = 0; j < 4; j++)
                    acc[i][j] = __builtin_amdgcn_mfma_f32_16x16x32_bf16(af[i], bf[j], acc[i][j], 0, 0, 0);
        }
    }

    // epilogue: C/D layout col=lane&15, row=(lane>>4)*4+r  [m89-verified]
    #pragma unroll
    for (int i = 0; i < 4; i++) {
        #pragma unroll
        for (int j = 0; j < 4; j++) {
            #pragma unroll
            for (int r = 0; r < 4; r++) {
                int row = row0 + wy * 64 + i * 16 + q4 * 4 + r;
                int gcol = colt * 128 + wx * 64 + j * 16 + l16;
                float v = acc[i][j][r] + bias[gcol];
                size_t oi = (size_t)row * out_ld + gcol;
                if (MODE == 0) {
                    ((unsigned short*)outp)[oi] = f2b(v);
                } else if (MODE == 1) {
                    float qv = b2f(qbf[(size_t)row * CC + gcol]);
                    ((unsigned short*)outp)[oi] = f2b(v * qv);
                } else if (MODE == 2) {
                    ((float*)outp)[oi] = v + xres[(size_t)row * CC + gcol];
                } else { // MODE 3
                    ((unsigned short*)outp)[oi] = f2b(gelu(v));
                }
            }
        }
    }
}

// ---------------- depthwise conv (SAME, zero pad) + GELU + gated accumulate ----------------
// Register-tiled: block = one (b,h) row, 256 threads = 32 chan-groups(4ch) x 8 w-tiles(7px).
// Per input row: 13-col window loaded once as uint2, converted once, reused for 7 outputs.
// out = gelu(conv(in));  acc = (L==0 ? 0 : acc) + gate[L] * out
template<int R, int L>
__global__ __launch_bounds__(256) void dwconv_k(
    const unsigned short* __restrict__ in, const float* __restrict__ w,
    unsigned short* __restrict__ out, const float* __restrict__ gates,
    unsigned short* acc)
{
    constexpr int KS = 2 * R + 1;
    constexpr int TW = 7;
    const int tid = threadIdx.x;
    const int cg = tid & 31;          // channel group of 4
    const int wt = tid >> 5;          // 0..7 -> pixels wt*7 .. wt*7+6
    const int bh = blockIdx.x;        // b*56 + h
    const int h = bh % HH;
    const int w0 = wt * TW;
    const int c0 = cg * 4;

    float accv[TW][4];
    #pragma unroll
    for (int i = 0; i < TW; i++) {
        #pragma unroll
        for (int e = 0; e < 4; e++) accv[i][e] = 0.0f;
    }

    #pragma unroll
    for (int kh = 0; kh < KS; kh++) {
        int hh = h + kh - R;
        if ((unsigned)hh >= (unsigned)HH) continue;   // block-uniform, no divergence
        // weight row for my 4 channels
        float wr[KS][4];
        #pragma unroll
        for (int kw = 0; kw < KS; kw++)
            *(float4*)&wr[kw][0] = *(const float4*)&w[(kh * KS + kw) * CC + c0];
        // input row window: columns w0-R .. w0+6+R
        const int rowbase = (bh - h + hh) * WW * CC + c0;   // (b*HH + hh)*WW*CC + c0
        float xr[TW + 2 * R][4];
        #pragma unroll
        for (int j = 0; j < TW + 2 * R; j++) {
            int wc = w0 + j - R;
            if ((unsigned)wc < (unsigned)WW) {
                uint2 pk = *(const uint2*)&in[(size_t)rowbase + wc * CC];
                cvt4(pk, &xr[j][0]);
            } else {
                #pragma unroll
                for (int e = 0; e < 4; e++) xr[j][e] = 0.0f;
            }
        }
        #pragma unroll
        for (int ow = 0; ow < TW; ow++) {
            #pragma unroll
            for (int kw = 0; kw < KS; kw++) {
                #pragma unroll
                for (int e = 0; e < 4; e++)
                    accv[ow][e] += xr[ow + kw][e] * wr[kw][e];
            }
        }
    }

    // epilogue
    #pragma unroll
    for (int ow = 0; ow < TW; ow++) {
        int token = bh * WW + w0 + ow;
        size_t idx = (size_t)token * CC + c0;
        float gval = gates[(size_t)token * 4 + L];
        float go[4], av[4];
        #pragma unroll
        for (int e = 0; e < 4; e++) go[e] = gelu(accv[ow][e]);
        if (L == 0) {
            #pragma unroll
            for (int e = 0; e < 4; e++) av[e] = go[e] * gval;
        } else {
            uint2 pv = *(const uint2*)&acc[idx];
            float pf[4]; cvt4(pv, pf);
            #pragma unroll
            for (int e = 0; e < 4; e++) av[e] = pf[e] + go[e] * gval;
        }
        *(uint2*)&out[idx] = pack4(go);
        *(uint2*)&acc[idx] = pack4(av);
    }
}

// ---------------- global mean over H*W, two-stage ----------------
__global__ void mean_part_k(const unsigned short* __restrict__ ctx2, float* __restrict__ part) {
    int b = blockIdx.x >> 4, ch = blockIdx.x & 15;
    int c = threadIdx.x; // 128 threads
    float s = 0.0f;
    size_t base = ((size_t)b * (HH * WW) + ch * 196) * CC + c;
    for (int p = 0; p < 196; p++) s += b2f(ctx2[base + (size_t)p * CC]);
    part[blockIdx.x * CC + c] = s;
}
__global__ void mean_fin_k(const float* __restrict__ part, float* __restrict__ cg) {
    int b = blockIdx.x, c = threadIdx.x;
    float s = 0.0f;
    for (int i = 0; i < 16; i++) s += part[(b * 16 + i) * CC + c];
    cg[b * CC + c] = gelu(s * (1.0f / 3136.0f));
}

// ---------------- acc += cg[b] * gate3 ----------------
__global__ __launch_bounds__(256) void addg3_k(
    unsigned short* acc, const float* __restrict__ gates, const float* __restrict__ cg)
{
    size_t idx = (size_t)blockIdx.x * 256 + threadIdx.x;
    int token = (int)(idx >> 7);
    int c = (int)(idx & 127);
    int b = token / (HH * WW);
    acc[idx] = f2b(b2f(acc[idx]) + cg[b * CC + c] * gates[(size_t)token * 4 + 3]);
}

extern "C" void kernel_launch(void* const* d_in, const int* in_sizes, int n_in,
                              void* d_out, int out_size, void* d_ws, size_t ws_size,
                              hipStream_t stream) {
    (void)in_sizes; (void)n_in; (void)out_size; (void)ws_size;
    const float* x      = (const float*)d_in[0];
    const float* f_w    = (const float*)d_in[1];
    const float* f_b    = (const float*)d_in[2];
    const float* k0     = (const float*)d_in[3];
    const float* k1     = (const float*)d_in[4];
    const float* k2     = (const float*)d_in[5];
    const float* h_w    = (const float*)d_in[6];
    const float* h_b    = (const float*)d_in[7];
    const float* proj_w = (const float*)d_in[8];
    const float* proj_b = (const float*)d_in[9];
    const float* ln1_g  = (const float*)d_in[10];
    const float* ln1_b  = (const float*)d_in[11];
    const float* ln2_g  = (const float*)d_in[12];
    const float* ln2_b  = (const float*)d_in[13];
    const float* fc1_w  = (const float*)d_in[14];
    const float* fc1_b  = (const float*)d_in[15];
    const float* fc2_w  = (const float*)d_in[16];
    const float* fc2_b  = (const float*)d_in[17];
    float* out = (float*)d_out;

    // ---- workspace bump allocator (256B aligned), total ~106.9 MB ----
    size_t off = 0;
    auto alloc = [&](size_t bytes) -> char* {
        char* p = (char*)d_ws + off;
        off += (bytes + 255) & ~(size_t)255;
        return p;
    };
    unsigned short* wt_f    = (unsigned short*)alloc(256 * 128 * 2);
    unsigned short* wt_h    = (unsigned short*)alloc(128 * 128 * 2);
    unsigned short* wt_proj = (unsigned short*)alloc(128 * 128 * 2);
    unsigned short* wt_fc1  = (unsigned short*)alloc(512 * 128 * 2);
    unsigned short* wt_fc2c = (unsigned short*)alloc(512 * 128 * 2);
    float*          zeros   = (float*)alloc(128 * 4);
    unsigned short* Y       = (unsigned short*)alloc((size_t)NT * CC * 2); // y -> ctx_all acc -> m
    unsigned short* Q       = (unsigned short*)alloc((size_t)NT * CC * 2); // q -> x_out -> G chunks
    float*          gates   = (float*)alloc((size_t)NT * 4 * 4);
    float*          part    = (float*)alloc(BB * 16 * CC * 4);
    float*          cg      = (float*)alloc(BB * CC * 4);

    // d_out (NT*128 fp32) doubles as two bf16 NT*128 planes for conv ping-pong
    unsigned short* p0 = (unsigned short*)d_out;
    unsigned short* p1 = p0 + (size_t)NT * CC;

    // ---- 0. weight prep ----
    transpose_bf16_k<<<(128 * 256 + 255) / 256, 256, 0, stream>>>(f_w, wt_f, 128, 256, 260);
    transpose_bf16_k<<<(128 * 128 + 255) / 256, 256, 0, stream>>>(h_w, wt_h, 128, 128, 128);
    transpose_bf16_k<<<(128 * 128 + 255) / 256, 256, 0, stream>>>(proj_w, wt_proj, 128, 128, 128);
    transpose_bf16_k<<<(128 * 512 + 255) / 256, 256, 0, stream>>>(fc1_w, wt_fc1, 128, 512, 512);
    transpose_fc2c_k<<<(512 * 128 + 255) / 256, 256, 0, stream>>>(fc2_w, wt_fc2c);
    zero_k<<<1, 256, 0, stream>>>(zeros, 128);

    // ---- 1. LN1 + gates -> Y, gates ----
    ln1_gates_k<<<NT / 4, 256, 0, stream>>>(x, ln1_g, ln1_b, f_w, f_b, Y, gates);

    // ---- 2. t = y @ f_w : q (cols 0..127) -> Q, ctx (cols 128..255) -> p1 ----
    gemm_k<0><<<dim3(NT / 128, 1), 256, 0, stream>>>(Y, wt_f, f_b, 128, 128, Q, nullptr, nullptr);
    gemm_k<0><<<dim3(NT / 128, 1), 256, 0, stream>>>(Y, wt_f + 128 * 128, f_b + 128, 128, 128, p1, nullptr, nullptr);

    // ---- 3-5. focal conv chain, ping-pong in d_out planes, acc in Y ----
    dwconv_k<1, 0><<<BB * HH, 256, 0, stream>>>(p1, k0, p0, gates, Y);
    dwconv_k<2, 1><<<BB * HH, 256, 0, stream>>>(p0, k1, p1, gates, Y);
    dwconv_k<3, 2><<<BB * HH, 256, 0, stream>>>(p1, k2, p0, gates, Y);

    // ---- 6-7. global context from ctx2 (p0) ----
    mean_part_k<<<BB * 16, 128, 0, stream>>>(p0, part);
    mean_fin_k<<<BB, 128, 0, stream>>>(part, cg);

    // ---- 8. ctx_all += cg * gate3 (in Y) ----
    addg3_k<<<NT * CC / 256, 256, 0, stream>>>(Y, gates, cg);

    // ---- 9. modulator GEMM, epilogue * q -> x_out (in place over Q) ----
    gemm_k<1><<<dim3(NT / 128, 1), 256, 0, stream>>>(Y, wt_h, h_b, 128, 128, Q, Q, nullptr);

    // ---- 10. proj GEMM, epilogue + x -> x1 (d_out, conv planes dead) ----
    gemm_k<2><<<dim3(NT / 128, 1), 256, 0, stream>>>(Q, wt_proj, proj_b, 128, 128, out, nullptr, x);

    // ---- 11. LN2 -> m (Y region) ----
    ln2_k<<<NT / 4, 256, 0, stream>>>(out, ln2_g, ln2_b, Y);

    // ---- 12. MLP in 4 hidden chunks: G = gelu(m@fc1_hc) -> Q; out += G@fc2_hc ----
    for (int hc = 0; hc < 4; hc++) {
        gemm_k<3><<<dim3(NT / 128, 1), 256, 0, stream>>>(Y, wt_fc1 + hc * 16384, fc1_b + hc * 128,
                                                         128, 128, Q, nullptr, nullptr);
        gemm_k<2><<<dim3(NT / 128, 1), 256, 0, stream>>>(Q, wt_fc2c + hc * 16384,
                                                         hc == 0 ? fc2_b : zeros,
                                                         128, 128, out, nullptr, out);
    }
}

// Round 4
// 1312.480 us; speedup vs baseline: 1.8574x; 1.0091x over previous
//
#include <hip/hip_runtime.h>
#include <hip/hip_bf16.h>

// FocalNet block, MI355X gfx950.
// R4: (a) all 3 depthwise convs fused into one LDS-resident kernel (image+halo
//     in 62x64 LDS ping-pong, ctx_all in registers, mean partials in-block);
//     (b) GEMMs load MFMA fragments direct from global (line-coalesced), LDS
//     only for layout transforms: h+proj fused, 4-chunk MLP fused (out RMW once);
//     (c) tanh-gelu (in-range err ~5e-4, threshold 0.11, margin 0.031).

#define NT 200704   // B*H*W
#define CC 128
#define HH 56
#define WW 56
#define BB 64

typedef short short8 __attribute__((ext_vector_type(8)));
typedef float f32x4  __attribute__((ext_vector_type(4)));

__device__ __forceinline__ float b2f(unsigned short u) {
    union { float f; unsigned int i; } v; v.i = ((unsigned int)u) << 16; return v.f;
}
__device__ __forceinline__ unsigned short f2b(float f) {
    __hip_bfloat16 h = __float2bfloat16(f);
    union { __hip_bfloat16 h; unsigned short u; } v; v.h = h; return v.u;
}
// tanh-form gelu: 0.5x(1+tanh(0.79788456(x+0.044715x^3))) == x * sigmoid(2y)
__device__ __forceinline__ float gelu(float x) {
    float x2 = x * x;
    float inner = fmaf(0.044715f * x2, x, x);
    float t = exp2f(inner * -2.302118070f);   // e^{-2*0.79788456*inner}
    return x * __builtin_amdgcn_rcpf(1.0f + t);
}
__device__ __forceinline__ void cvt4(uint2 p, float* o) {
    union { float f; unsigned int i; } v;
    v.i = p.x << 16;         o[0] = v.f;
    v.i = p.x & 0xffff0000u; o[1] = v.f;
    v.i = p.y << 16;         o[2] = v.f;
    v.i = p.y & 0xffff0000u; o[3] = v.f;
}
__device__ __forceinline__ uint2 pack4(const float* s) {
    uint2 r;
    r.x = (unsigned int)f2b(s[0]) | ((unsigned int)f2b(s[1]) << 16);
    r.y = (unsigned int)f2b(s[2]) | ((unsigned int)f2b(s[3]) << 16);
    return r;
}
__device__ __forceinline__ short8 ldfrag_g(const unsigned short* p) {
    union { uint4 u; short8 s; } v;
    v.u = *(const uint4*)p;
    return v.s;
}
__device__ __forceinline__ short8 ldfrag_s(const unsigned short* p) {
    return *(const short8*)p;
}

// ---------------- weight prep: fp32 (K,M) row-major -> bf16 (M,K) ----------------
__global__ void transpose_bf16_k(const float* __restrict__ src, unsigned short* __restrict__ dst,
                                 int K, int M, int src_ld) {
    int idx = blockIdx.x * 256 + threadIdx.x;
    if (idx >= K * M) return;
    int k = idx / M, m = idx - k * M;
    dst[m * K + k] = f2b(src[k * src_ld + m]);
}
// fc2_w (512,128) -> (4 chunks, 128 out, 128 k-local)
__global__ void transpose_fc2c_k(const float* __restrict__ src, unsigned short* __restrict__ dst) {
    int idx = blockIdx.x * 256 + threadIdx.x;
    if (idx >= 512 * 128) return;
    int k = idx >> 7, m = idx & 127;
    int hc = k >> 7, kl = k & 127;
    dst[hc * 16384 + m * 128 + kl] = f2b(src[k * 128 + m]);
}

// ---------------- LN1 + gate dots (wave per token) ----------------
__global__ __launch_bounds__(256) void ln1_gates_k(
    const float* __restrict__ x, const float* __restrict__ g, const float* __restrict__ bta,
    const float* __restrict__ fw, const float* __restrict__ fb,
    unsigned short* __restrict__ ybf, float* __restrict__ gates)
{
    int lane = threadIdx.x & 63, wv = threadIdx.x >> 6;
    int token = blockIdx.x * 4 + wv;
    float2 xv = *(const float2*)&x[(size_t)token * CC + lane * 2];
    float s = xv.x + xv.y;
    for (int o = 32; o; o >>= 1) s += __shfl_xor(s, o);
    float mu = s * (1.0f / 128.0f);
    float d0 = xv.x - mu, d1 = xv.y - mu;
    float q2 = d0 * d0 + d1 * d1;
    for (int o = 32; o; o >>= 1) q2 += __shfl_xor(q2, o);
    float rs = rsqrtf(q2 * (1.0f / 128.0f) + 1e-5f);
    float y0 = d0 * rs * g[2 * lane] + bta[2 * lane];
    float y1 = d1 * rs * g[2 * lane + 1] + bta[2 * lane + 1];
    unsigned int pk = (unsigned int)f2b(y0) | ((unsigned int)f2b(y1) << 16);
    ((unsigned int*)ybf)[(size_t)token * 64 + lane] = pk;
    float ga[4];
    #pragma unroll
    for (int gg = 0; gg < 4; gg++)
        ga[gg] = y0 * fw[(2 * lane) * 260 + 256 + gg] + y1 * fw[(2 * lane + 1) * 260 + 256 + gg];
    for (int o = 32; o; o >>= 1) {
        #pragma unroll
        for (int gg = 0; gg < 4; gg++) ga[gg] += __shfl_xor(ga[gg], o);
    }
    if (lane == 0) {
        float4 gv = make_float4(ga[0] + fb[256], ga[1] + fb[257], ga[2] + fb[258], ga[3] + fb[259]);
        *(float4*)&gates[(size_t)token * 4] = gv;
    }
}

// ---------------- LN2 (wave per token) ----------------
__global__ __launch_bounds__(256) void ln2_k(
    const float* __restrict__ x, const float* __restrict__ g, const float* __restrict__ bta,
    unsigned short* __restrict__ ybf)
{
    int lane = threadIdx.x & 63, wv = threadIdx.x >> 6;
    int token = blockIdx.x * 4 + wv;
    float2 xv = *(const float2*)&x[(size_t)token * CC + lane * 2];
    float s = xv.x + xv.y;
    for (int o = 32; o; o >>= 1) s += __shfl_xor(s, o);
    float mu = s * (1.0f / 128.0f);
    float d0 = xv.x - mu, d1 = xv.y - mu;
    float q2 = d0 * d0 + d1 * d1;
    for (int o = 32; o; o >>= 1) q2 += __shfl_xor(q2, o);
    float rs = rsqrtf(q2 * (1.0f / 128.0f) + 1e-5f);
    float y0 = d0 * rs * g[2 * lane] + bta[2 * lane];
    float y1 = d1 * rs * g[2 * lane + 1] + bta[2 * lane + 1];
    unsigned int pk = (unsigned int)f2b(y0) | ((unsigned int)f2b(y1) << 16);
    ((unsigned int*)ybf)[(size_t)token * 64 + lane] = pk;
}

// ================= GEMM building block macros =================
// 128x128 tile, 4 waves 2x2, wave does 64x64 via 4x4 mfma_16x16x32_bf16.
// A/B frags loaded direct from global (wave covers 16 whole cache lines/inst).

#define GEMM_IDS \
    const int row0 = blockIdx.x * 128; \
    const int lane = threadIdx.x & 63, wv = threadIdx.x >> 6; \
    const int wy = wv >> 1, wx = wv & 1; \
    const int q4 = lane >> 4, l16 = lane & 15; (void)row0;

#define ZERO_ACC(acc) \
    _Pragma("unroll") for (int i = 0; i < 4; i++) \
    _Pragma("unroll") for (int j = 0; j < 4; j++) acc[i][j] = (f32x4)0.0f;

#define MFMA_ALL(acc, af, bf) \
    _Pragma("unroll") for (int i = 0; i < 4; i++) \
    _Pragma("unroll") for (int j = 0; j < 4; j++) \
        acc[i][j] = __builtin_amdgcn_mfma_f32_16x16x32_bf16(af[i], bf[j], acc[i][j], 0, 0, 0);

// ---------------- fused q+ctx GEMM: t = y @ f_w[:, :256] ----------------
__global__ __launch_bounds__(256) void gemm_f2_k(
    const unsigned short* __restrict__ A, const unsigned short* __restrict__ Wt,
    const float* __restrict__ fb,
    unsigned short* __restrict__ outq, unsigned short* __restrict__ outc)
{
    GEMM_IDS;
    for (int mo = 0; mo < 2; mo++) {
        f32x4 acc[4][4];
        ZERO_ACC(acc);
        for (int kk = 0; kk < 128; kk += 32) {
            short8 af[4], bf[4];
            #pragma unroll
            for (int i = 0; i < 4; i++)
                af[i] = ldfrag_g(&A[(size_t)(row0 + wy * 64 + i * 16 + l16) * 128 + kk + q4 * 8]);
            #pragma unroll
            for (int j = 0; j < 4; j++)
                bf[j] = ldfrag_g(&Wt[(size_t)(mo * 128 + wx * 64 + j * 16 + l16) * 128 + kk + q4 * 8]);
            MFMA_ALL(acc, af, bf);
        }
        unsigned short* op = mo ? outc : outq;
        #pragma unroll
        for (int i = 0; i < 4; i++)
            #pragma unroll
            for (int j = 0; j < 4; j++)
                #pragma unroll
                for (int rr = 0; rr < 4; rr++) {
                    int row = row0 + wy * 64 + i * 16 + q4 * 4 + rr;
                    int col = wx * 64 + j * 16 + l16;
                    op[(size_t)row * CC + col] = f2b(acc[i][j][rr] + fb[mo * 128 + col]);
                }
    }
}

// ---------------- fused h + proj GEMM ----------------
// x_out = q * (ctx_all @ h_w + h_b);  x1 = x + x_out @ proj_w + proj_b -> d_out (fp32)
__global__ __launch_bounds__(256) void gemm_hproj_k(
    const unsigned short* __restrict__ CA, const unsigned short* __restrict__ Wh,
    const float* __restrict__ hb, const unsigned short* __restrict__ Qm,
    const unsigned short* __restrict__ Wp, const float* __restrict__ pb,
    const float* __restrict__ xin, float* __restrict__ outp)
{
    __shared__ unsigned short Gs[128 * 136];
    GEMM_IDS;
    f32x4 acc[4][4];
    ZERO_ACC(acc);
    for (int kk = 0; kk < 128; kk += 32) {
        short8 af[4], bf[4];
        #pragma unroll
        for (int i = 0; i < 4; i++)
            af[i] = ldfrag_g(&CA[(size_t)(row0 + wy * 64 + i * 16 + l16) * 128 + kk + q4 * 8]);
        #pragma unroll
        for (int j = 0; j < 4; j++)
            bf[j] = ldfrag_g(&Wh[(size_t)(wx * 64 + j * 16 + l16) * 128 + kk + q4 * 8]);
        MFMA_ALL(acc, af, bf);
    }
    #pragma unroll
    for (int i = 0; i < 4; i++)
        #pragma unroll
        for (int j = 0; j < 4; j++)
            #pragma unroll
            for (int rr = 0; rr < 4; rr++) {
                int row_l = wy * 64 + i * 16 + q4 * 4 + rr;
                int col_l = wx * 64 + j * 16 + l16;
                float v = acc[i][j][rr] + hb[col_l];
                float qv = b2f(Qm[(size_t)(row0 + row_l) * CC + col_l]);
                Gs[row_l * 136 + col_l] = f2b(v * qv);
            }
    __syncthreads();
    ZERO_ACC(acc);
    for (int kk = 0; kk < 128; kk += 32) {
        short8 af[4], bf[4];
        #pragma unroll
        for (int i = 0; i < 4; i++)
            af[i] = ldfrag_s(&Gs[(wy * 64 + i * 16 + l16) * 136 + kk + q4 * 8]);
        #pragma unroll
        for (int j = 0; j < 4; j++)
            bf[j] = ldfrag_g(&Wp[(size_t)(wx * 64 + j * 16 + l16) * 128 + kk + q4 * 8]);
        MFMA_ALL(acc, af, bf);
    }
    #pragma unroll
    for (int i = 0; i < 4; i++)
        #pragma unroll
        for (int j = 0; j < 4; j++)
            #pragma unroll
            for (int rr = 0; rr < 4; rr++) {
                int row = row0 + wy * 64 + i * 16 + q4 * 4 + rr;
                int col = wx * 64 + j * 16 + l16;
                size_t oi = (size_t)row * CC + col;
                outp[oi] = acc[i][j][rr] + pb[col] + xin[oi];
            }
}

// ---------------- fused MLP: out += gelu(m@fc1+b1)@fc2 + b2 (4 hidden chunks) ----------------
__global__ __launch_bounds__(256) void gemm_mlp_k(
    const unsigned short* __restrict__ M, const unsigned short* __restrict__ W1,
    const float* __restrict__ b1, const unsigned short* __restrict__ W2,
    const float* __restrict__ b2, float* __restrict__ outp)
{
    __shared__ unsigned short Gs[128 * 136];
    GEMM_IDS;
    f32x4 accO[4][4];
    ZERO_ACC(accO);
    for (int hc = 0; hc < 4; hc++) {
        f32x4 accG[4][4];
        ZERO_ACC(accG);
        for (int kk = 0; kk < 128; kk += 32) {
            short8 af[4], bf[4];
            #pragma unroll
            for (int i = 0; i < 4; i++)
                af[i] = ldfrag_g(&M[(size_t)(row0 + wy * 64 + i * 16 + l16) * 128 + kk + q4 * 8]);
            #pragma unroll
            for (int j = 0; j < 4; j++)
                bf[j] = ldfrag_g(&W1[(size_t)(hc * 128 + wx * 64 + j * 16 + l16) * 128 + kk + q4 * 8]);
            MFMA_ALL(accG, af, bf);
        }
        __syncthreads();   // prior chunk's Gs reads complete
        #pragma unroll
        for (int i = 0; i < 4; i++)
            #pragma unroll
            for (int j = 0; j < 4; j++)
                #pragma unroll
                for (int rr = 0; rr < 4; rr++) {
                    int row_l = wy * 64 + i * 16 + q4 * 4 + rr;
                    int col_l = wx * 64 + j * 16 + l16;
                    Gs[row_l * 136 + col_l] = f2b(gelu(accG[i][j][rr] + b1[hc * 128 + col_l]));
                }
        __syncthreads();
        for (int kk = 0; kk < 128; kk += 32) {
            short8 af[4], bf[4];
            #pragma unroll
            for (int i = 0; i < 4; i++)
                af[i] = ldfrag_s(&Gs[(wy * 64 + i * 16 + l16) * 136 + kk + q4 * 8]);
            #pragma unroll
            for (int j = 0; j < 4; j++)
                bf[j] = ldfrag_g(&W2[(size_t)hc * 16384 + (wx * 64 + j * 16 + l16) * 128 + kk + q4 * 8]);
            MFMA_ALL(accO, af, bf);
        }
    }
    #pragma unroll
    for (int i = 0; i < 4; i++)
        #pragma unroll
        for (int j = 0; j < 4; j++)
            #pragma unroll
            for (int rr = 0; rr < 4; rr++) {
                int row = row0 + wy * 64 + i * 16 + q4 * 4 + rr;
                int col = wx * 64 + j * 16 + l16;
                size_t oi = (size_t)row * CC + col;
                outp[oi] = accO[i][j][rr] + b2[col] + outp[oi];
            }
}

// ---------------- fused 3-level depthwise conv chain ----------------
// Block = (batch image, 4-channel slab). 62x64 LDS ping-pong (radius-3 zero halo).
// Thread = 7-px row strip. ctx_all accumulated in registers; mean partials in-block.
template<int R, bool SUM>
__device__ __forceinline__ void conv_level(
    const uint2* __restrict__ bin, uint2* __restrict__ bout,
    const float4* __restrict__ wl, const float* __restrict__ gates,
    int r, int w0, int tok0, int level, float creg[7][4], float psum[4])
{
    constexpr int KS = 2 * R + 1;
    float acc7[7][4];
    #pragma unroll
    for (int i = 0; i < 7; i++)
        #pragma unroll
        for (int e = 0; e < 4; e++) acc7[i][e] = 0.0f;
    #pragma unroll
    for (int kh = 0; kh < KS; kh++) {
        float wr[KS][4];
        #pragma unroll
        for (int kw = 0; kw < KS; kw++) {
            float4 w4 = wl[kh * KS + kw];
            wr[kw][0] = w4.x; wr[kw][1] = w4.y; wr[kw][2] = w4.z; wr[kw][3] = w4.w;
        }
        const uint2* rp = &bin[(r + kh + 3 - R) * 64 + (w0 + 3 - R)];
        float xw[7 + 2 * R][4];
        #pragma unroll
        for (int j = 0; j < 7 + 2 * R; j++) cvt4(rp[j], xw[j]);
        #pragma unroll
        for (int ow = 0; ow < 7; ow++)
            #pragma unroll
            for (int kw = 0; kw < KS; kw++)
                #pragma unroll
                for (int e = 0; e < 4; e++)
                    acc7[ow][e] += xw[ow + kw][e] * wr[kw][e];
    }
    #pragma unroll
    for (int ow = 0; ow < 7; ow++) {
        float gt = gates[(size_t)(tok0 + ow) * 4 + level];
        float g4[4];
        #pragma unroll
        for (int e = 0; e < 4; e++) {
            float gg = gelu(acc7[ow][e]);
            g4[e] = gg;
            creg[ow][e] += gg * gt;
            if (SUM) psum[e] += gg;
        }
        bout[(r + 3) * 64 + (w0 + 3 + ow)] = pack4(g4);
    }
}

__global__ __launch_bounds__(448) void dwconv_fused_k(
    const unsigned short* __restrict__ cin,
    const float* __restrict__ k0w, const float* __restrict__ k1w, const float* __restrict__ k2w,
    const float* __restrict__ gates,
    unsigned short* __restrict__ cout, float* __restrict__ part)
{
    __shared__ uint2 bufA[62 * 64];
    __shared__ uint2 bufB[62 * 64];
    __shared__ float4 wl[49];
    __shared__ float wred[7][4];
    const int tid = threadIdx.x;
    const int b = blockIdx.x, slab = blockIdx.y;

    for (int i = tid; i < 62 * 64; i += 448) {
        bufA[i] = make_uint2(0u, 0u);
        bufB[i] = make_uint2(0u, 0u);
    }
    __syncthreads();
    for (int px = tid; px < 3136; px += 448) {
        int r = px / 56, c = px - r * 56;
        bufA[(r + 3) * 64 + c + 3] = *(const uint2*)&cin[((size_t)b * 3136 + px) * CC + slab * 4];
    }
    if (tid < 9) wl[tid] = *(const float4*)&k0w[tid * CC + slab * 4];
    __syncthreads();

    const int r = tid >> 3, wt = tid & 7, w0 = wt * 7;
    const int tok0 = b * 3136 + r * 56 + w0;
    float creg[7][4];
    #pragma unroll
    for (int i = 0; i < 7; i++)
        #pragma unroll
        for (int e = 0; e < 4; e++) creg[i][e] = 0.0f;
    float psum[4] = {0.0f, 0.0f, 0.0f, 0.0f};

    conv_level<1, false>(bufA, bufB, wl, gates, r, w0, tok0, 0, creg, psum);
    __syncthreads();
    if (tid < 25) wl[tid] = *(const float4*)&k1w[tid * CC + slab * 4];
    __syncthreads();
    conv_level<2, false>(bufB, bufA, wl, gates, r, w0, tok0, 1, creg, psum);
    __syncthreads();
    if (tid < 49) wl[tid] = *(const float4*)&k2w[tid * CC + slab * 4];
    __syncthreads();
    conv_level<3, true>(bufA, bufB, wl, gates, r, w0, tok0, 2, creg, psum);

    // write ctx_all (global-context term added later by addg3)
    #pragma unroll
    for (int ow = 0; ow < 7; ow++)
        *(uint2*)&cout[((size_t)tok0 + ow) * CC + slab * 4] = pack4(creg[ow]);

    // block partial sums for the global mean of ctx2
    #pragma unroll
    for (int e = 0; e < 4; e++)
        for (int o = 32; o; o >>= 1) psum[e] += __shfl_xor(psum[e], o);
    if ((tid & 63) == 0) {
        #pragma unroll
        for (int e = 0; e < 4; e++) wred[tid >> 6][e] = psum[e];
    }
    __syncthreads();
    if (tid == 0) {
        float s0 = 0, s1 = 0, s2 = 0, s3 = 0;
        for (int w2 = 0; w2 < 7; w2++) {
            s0 += wred[w2][0]; s1 += wred[w2][1]; s2 += wred[w2][2]; s3 += wred[w2][3];
        }
        float4 res = make_float4(s0, s1, s2, s3);
        *(float4*)&part[((size_t)b * 32 + slab) * 4] = res;
    }
}

// ---------------- cg = gelu(mean) ----------------
__global__ void mean_fin_k(const float* __restrict__ part, float* __restrict__ cg) {
    int b = blockIdx.x, c = threadIdx.x;
    cg[b * CC + c] = gelu(part[b * CC + c] * (1.0f / 3136.0f));
}

// ---------------- acc += cg[b] * gate3 ----------------
__global__ __launch_bounds__(256) void addg3_k(
    unsigned short* acc, const float* __restrict__ gates, const float* __restrict__ cg)
{
    size_t idx = (size_t)blockIdx.x * 256 + threadIdx.x;
    int token = (int)(idx >> 7);
    int c = (int)(idx & 127);
    int b = token / (HH * WW);
    acc[idx] = f2b(b2f(acc[idx]) + cg[b * CC + c] * gates[(size_t)token * 4 + 3]);
}

extern "C" void kernel_launch(void* const* d_in, const int* in_sizes, int n_in,
                              void* d_out, int out_size, void* d_ws, size_t ws_size,
                              hipStream_t stream) {
    (void)in_sizes; (void)n_in; (void)out_size; (void)ws_size;
    const float* x      = (const float*)d_in[0];
    const float* f_w    = (const float*)d_in[1];
    const float* f_b    = (const float*)d_in[2];
    const float* k0     = (const float*)d_in[3];
    const float* k1     = (const float*)d_in[4];
    const float* k2     = (const float*)d_in[5];
    const float* h_w    = (const float*)d_in[6];
    const float* h_b    = (const float*)d_in[7];
    const float* proj_w = (const float*)d_in[8];
    const float* proj_b = (const float*)d_in[9];
    const float* ln1_g  = (const float*)d_in[10];
    const float* ln1_b  = (const float*)d_in[11];
    const float* ln2_g  = (const float*)d_in[12];
    const float* ln2_b  = (const float*)d_in[13];
    const float* fc1_w  = (const float*)d_in[14];
    const float* fc1_b  = (const float*)d_in[15];
    const float* fc2_w  = (const float*)d_in[16];
    const float* fc2_b  = (const float*)d_in[17];
    float* out = (float*)d_out;

    // ---- workspace bump allocator (256B aligned), total ~103.3 MB ----
    size_t off = 0;
    auto alloc = [&](size_t bytes) -> char* {
        char* p = (char*)d_ws + off;
        off += (bytes + 255) & ~(size_t)255;
        return p;
    };
    unsigned short* wt_f    = (unsigned short*)alloc(256 * 128 * 2);
    unsigned short* wt_h    = (unsigned short*)alloc(128 * 128 * 2);
    unsigned short* wt_proj = (unsigned short*)alloc(128 * 128 * 2);
    unsigned short* wt_fc1  = (unsigned short*)alloc(512 * 128 * 2);
    unsigned short* wt_fc2c = (unsigned short*)alloc(512 * 128 * 2);
    unsigned short* Y       = (unsigned short*)alloc((size_t)NT * CC * 2); // y -> ctx_all -> m
    unsigned short* Q       = (unsigned short*)alloc((size_t)NT * CC * 2); // q
    float*          gates   = (float*)alloc((size_t)NT * 4 * 4);
    float*          part    = (float*)alloc(BB * CC * 4);
    float*          cg      = (float*)alloc(BB * CC * 4);

    // ctx lives in d_out's upper half until the conv consumes it
    unsigned short* p1 = (unsigned short*)d_out + (size_t)NT * CC;

    // ---- 0. weight prep ----
    transpose_bf16_k<<<(128 * 256 + 255) / 256, 256, 0, stream>>>(f_w, wt_f, 128, 256, 260);
    transpose_bf16_k<<<(128 * 128 + 255) / 256, 256, 0, stream>>>(h_w, wt_h, 128, 128, 128);
    transpose_bf16_k<<<(128 * 128 + 255) / 256, 256, 0, stream>>>(proj_w, wt_proj, 128, 128, 128);
    transpose_bf16_k<<<(128 * 512 + 255) / 256, 256, 0, stream>>>(fc1_w, wt_fc1, 128, 512, 512);
    transpose_fc2c_k<<<(512 * 128 + 255) / 256, 256, 0, stream>>>(fc2_w, wt_fc2c);

    // ---- 1. LN1 + gates ----
    ln1_gates_k<<<NT / 4, 256, 0, stream>>>(x, ln1_g, ln1_b, f_w, f_b, Y, gates);

    // ---- 2. q + ctx in one GEMM kernel ----
    gemm_f2_k<<<NT / 128, 256, 0, stream>>>(Y, wt_f, f_b, Q, p1);

    // ---- 3. fused conv chain -> ctx_all (Y), mean partials ----
    dwconv_fused_k<<<dim3(BB, 32), 448, 0, stream>>>(p1, k0, k1, k2, gates, Y, part);

    // ---- 4. global context ----
    mean_fin_k<<<BB, 128, 0, stream>>>(part, cg);
    addg3_k<<<NT * CC / 256, 256, 0, stream>>>(Y, gates, cg);

    // ---- 5. fused h+proj -> x1 (d_out fp32) ----
    gemm_hproj_k<<<NT / 128, 256, 0, stream>>>(Y, wt_h, h_b, Q, wt_proj, proj_b, x, out);

    // ---- 6. LN2 -> m (Y) ----
    ln2_k<<<NT / 4, 256, 0, stream>>>(out, ln2_g, ln2_b, Y);

    // ---- 7. fused MLP, out RMW once ----
    gemm_mlp_k<<<NT / 128, 256, 0, stream>>>(Y, wt_fc1, fc1_b, wt_fc2c, fc2_b, out);
}